// Round 17
// baseline (107.774 us; speedup 1.0000x reference)
//
#include <hip/hip_runtime.h>

// GCNConv(8->64), self-loops, symmetric norm.
// out[c] = ( dis[c] * sum_e dis[r]*ew*x[r]  +  dis[c]^2 * x[c] ) @ W + b
//
// v17 = v16 + contended-LDS-atomic elimination (r15 quantified heavy-collision
// LDS atomics at ~7us/M):
//   * nodestat: per-wave cnt16/dw16 [16][128] (collisions 8-way -> ~0.5-way)
//     + 16-step column reduce.
//   * aggfuse stage: two-phase deterministic rank — per-wave wcnt[16][128]
//     rank atomics (low contention), column scan for per-(wave,lc) bases,
//     edges held in regs (<=6/thread/round), place without global rank
//     atomics. nxt[] carries per-lc bases across 6144-edge rounds.
//
// Payload pack (u64): ew_bits(32) | row(24) | lcol(8). Valid for N <= 2^24.

#define NBMAX 1024          // max bins => N <= 131072 (fallback beyond)
#define PSH   7
#define BINSZ 128
#define TILE  6144          // edges per tile
#define EPT   6             // TILE / 1024 threads
#define CAP   6144          // max edges per bin staged in LDS by aggfuse

static inline size_t ws_align(size_t x) { return (x + 255) & ~(size_t)255; }

// per-block int64-layout detect: odd 32-bit words of int64 indices (<2^31)
// are all zero; random int32 col values make the OR nonzero essentially surely.
__device__ __forceinline__ bool detect64(const unsigned* w, int E) {
    __shared__ unsigned det;
    if (threadIdx.x == 0) det = 0u;
    __syncthreads();
    int lim = E < 1024 ? E : 1024;
    unsigned v = 0;
    for (int i = threadIdx.x; i < lim; i += blockDim.x) v |= w[2 * i + 1];
    if (v) atomicOr(&det, 1u);
    __syncthreads();
    return det == 0u;
}

// ---- per-tile histogram over destination bins -> tcnt[tile][bin] ----
__global__ __launch_bounds__(1024)
void hist_k(const void* ei, unsigned* tcnt, int E, int NB, int ntiles) {
    __shared__ unsigned lh[NBMAX];
    const bool is64 = detect64((const unsigned*)ei, E);
    const int* e32 = (const int*)ei;
    const long long* e64 = (const long long*)ei;
    const int t = threadIdx.x;
    for (int tile = blockIdx.x; tile < ntiles; tile += gridDim.x) {
        int base = tile * TILE;
        int tc = E - base; if (tc > TILE) tc = TILE;
        for (int i = t; i < NB; i += 1024) lh[i] = 0u;
        __syncthreads();
        for (int e = base + t; e < base + tc; e += 1024) {
            int c = is64 ? (int)e64[E + e] : e32[E + e];
            atomicAdd(&lh[c >> PSH], 1u);
        }
        __syncthreads();
        for (int i = t; i < NB; i += 1024)
            tcnt[(size_t)tile * NB + i] = lh[i];
        __syncthreads();
    }
}

// ---- column scan: tcnt[:, b] -> exclusive prefix (in place) + cnt[b] ----
__global__ void scan2_k(unsigned* tcnt, unsigned* cnt, int NB, int ntiles) {
    int b = blockIdx.x, lane = threadIdx.x;   // 64 threads
    unsigned run = 0;
    for (int base = 0; base < ntiles; base += 64) {
        int i = base + lane;
        unsigned v = (i < ntiles) ? tcnt[(size_t)i * NB + b] : 0u;
        unsigned s = v;
        #pragma unroll
        for (int d = 1; d < 64; d <<= 1) {
            unsigned u = __shfl_up(s, d);
            if (lane >= d) s += u;
        }
        if (i < ntiles) tcnt[(size_t)i * NB + b] = run + s - v;
        run += __shfl(s, 63);
    }
    if (lane == 0) cnt[b] = run;
}

// ---- exclusive scan of cnt[NB] -> offs[NB+1] (shfl) ----
__global__ void scan_k(const unsigned* cnt, unsigned* offs, int NB) {
    __shared__ unsigned wsum[16];
    int t = threadIdx.x, lane = t & 63, wv = t >> 6;   // 1024 threads
    unsigned v0 = (t < NB) ? cnt[t] : 0u;
    unsigned s = v0;
    #pragma unroll
    for (int d = 1; d < 64; d <<= 1) {
        unsigned u = __shfl_up(s, d);
        if (lane >= d) s += u;
    }
    if (lane == 63) wsum[wv] = s;
    __syncthreads();
    if (t < 16) {
        unsigned w = wsum[t];
        #pragma unroll
        for (int d = 1; d < 16; d <<= 1) {
            unsigned u = __shfl_up(w, d, 16);
            if (t >= d) w += u;
        }
        wsum[t] = w;
    }
    __syncthreads();
    unsigned excl = s - v0 + (wv ? wsum[wv - 1] : 0u);
    if (t < NB) offs[t] = excl;
    if (t == NB - 1) offs[NB] = excl + v0;
}

// ---- scatter: staged LDS bin-sort, deterministic run bases, coalesced
// flush; XCD-swizzled tile order (adjacent tiles -> same XCD) ----
__global__ __launch_bounds__(1024)
void scat_k(const void* ei, const float* ea, const unsigned* offs,
            const unsigned* tcnt, unsigned long long* pay,
            int E, int NB, int ntiles, int cpx) {
    __shared__ unsigned long long lp[TILE];   // 48KB
    __shared__ unsigned short lbin[TILE];     // 12KB
    __shared__ unsigned lh[NBMAX];
    __shared__ unsigned lo[NBMAX];
    __shared__ unsigned tb[NBMAX];
    __shared__ unsigned wsum[16];
    const bool is64 = detect64((const unsigned*)ei, E);
    const int* e32 = (const int*)ei;
    const long long* e64 = (const long long*)ei;
    const int t = threadIdx.x, lane = t & 63, wv = t >> 6;
    const int sgrid = cpx * 8;

    for (int ii = blockIdx.x; ii < sgrid; ii += gridDim.x) {
        int tile = (ii & 7) * cpx + (ii >> 3);   // XCD-contiguous chunks
        if (tile >= ntiles) continue;
        int base = tile * TILE;
        int tc = E - base; if (tc > TILE) tc = TILE;

        for (int i = t; i < NB; i += 1024) lh[i] = 0u;
        __syncthreads();

        int bn[EPT]; unsigned rk[EPT]; unsigned long long pv[EPT];
        #pragma unroll
        for (int i = 0; i < EPT; ++i) {
            int e = base + i * 1024 + t;
            bn[i] = -1;
            if (e < base + tc) {
                int c, r;
                if (is64) { c = (int)e64[E + e]; r = (int)e64[e]; }
                else      { c = e32[E + e];      r = e32[e]; }
                float w = ea[e];
                bn[i] = c >> PSH;
                pv[i] = ((unsigned long long)__float_as_uint(w) << 32)
                        | ((unsigned)r << 8) | (unsigned)(c & (BINSZ - 1));
                rk[i] = atomicAdd(&lh[bn[i]], 1u);
            }
        }
        __syncthreads();

        unsigned v0 = (t < NB) ? lh[t] : 0u;
        unsigned s = v0;
        #pragma unroll
        for (int d = 1; d < 64; d <<= 1) {
            unsigned u = __shfl_up(s, d);
            if (lane >= d) s += u;
        }
        if (lane == 63) wsum[wv] = s;
        __syncthreads();
        if (t < 16) {
            unsigned w = wsum[t];
            #pragma unroll
            for (int d = 1; d < 16; d <<= 1) {
                unsigned u = __shfl_up(w, d, 16);
                if (t >= d) w += u;
            }
            wsum[t] = w;
        }
        __syncthreads();
        unsigned excl = s - v0 + (wv ? wsum[wv - 1] : 0u);
        if (t < NB) {
            lo[t] = excl;
            tb[t] = offs[t] + tcnt[(size_t)tile * NB + t];
        }
        __syncthreads();

        #pragma unroll
        for (int i = 0; i < EPT; ++i)
            if (bn[i] >= 0) {
                unsigned pos = lo[bn[i]] + rk[i];
                lp[pos] = pv[i];
                lbin[pos] = (unsigned short)bn[i];
            }
        __syncthreads();

        // flush: coalesced per-run segments
        for (int q = t; q < tc; q += 1024) {
            int a = lbin[q];
            pay[(size_t)tb[a] + (unsigned)q - lo[a]] = lp[q];
        }
        __syncthreads();
    }
}

// ---- A: per-bin node stats -> noffs, dis, y = dis*x ----
// per-wave cnt/dw split: collisions 8-way -> ~0.5-way.
__global__ __launch_bounds__(1024)
void nodestat_k(const unsigned long long* pay, const unsigned* offs,
                unsigned* noffs, float* dis, const float* x, float* y,
                int N, int E) {
    __shared__ unsigned cnt16[16][BINSZ];     // 8KB per-wave counts
    __shared__ float    dw16[16][BINSZ];      // 8KB per-wave weighted deg
    __shared__ float sdis[BINSZ];
    __shared__ unsigned wpart[2];
    int b = blockIdx.x, t = threadIdx.x, lane = t & 63, wv = t >> 6;
    for (int i = t; i < 16 * BINSZ; i += 1024) {
        ((unsigned*)cnt16)[i] = 0u;
        ((float*)dw16)[i] = 0.f;
    }
    if (b == 0 && t == 0) noffs[N] = (unsigned)E;
    __syncthreads();
    unsigned base = offs[b], len = offs[b + 1] - base;
    for (unsigned j = t; j < len; j += 1024) {
        unsigned long long p = pay[base + j];
        unsigned lc = (unsigned)p & 255u;
        atomicAdd(&cnt16[wv][lc], 1u);
        atomicAdd(&dw16[wv][lc], __uint_as_float((unsigned)(p >> 32)));
    }
    __syncthreads();
    // reduce across waves (thread t<128 owns lc=t)
    unsigned cv = 0; float dwv = 0.f;
    if (t < BINSZ) {
        #pragma unroll
        for (int w = 0; w < 16; ++w) { cv += cnt16[w][t]; dwv += dw16[w][t]; }
    }
    // scan 128 via 2 waves of shfl
    unsigned v0 = (t < BINSZ) ? cv : 0u;
    unsigned s = v0;
    #pragma unroll
    for (int d = 1; d < 64; d <<= 1) {
        unsigned u = __shfl_up(s, d);
        if (lane >= d) s += u;
    }
    if (t < BINSZ && lane == 63) wpart[wv] = s;
    __syncthreads();
    if (t < BINSZ) {
        unsigned excl = s - v0 + (wv == 1 ? wpart[0] : 0u);
        int node = b * BINSZ + t;
        float dval = 0.f;
        if (node < N) {
            noffs[node] = base + excl;
            float d = 1.0f + dwv;
            dval = (d > 0.f) ? rsqrtf(d) : 0.f;
            dis[node] = dval;
        }
        sdis[t] = dval;
    }
    __syncthreads();
    int gi = b * (BINSZ * 8) + t;             // 1024 == BINSZ*8
    if (gi < N * 8) y[gi] = sdis[t >> 3] * x[gi];
}

// ---- B: fused per-bin node-sort (LDS) + aggregate + transform + out ----
// stage: two-phase deterministic rank (per-wave wcnt + column scan), edges
// in registers; accumulate: 4 nodes/wave, 3 shfls/node (v14 winner).
__global__ __launch_bounds__(1024)
void aggfuse_k(const unsigned long long* pay, const unsigned* offs,
               const unsigned* noffs, const float* dis, const float* y,
               const float* Wm, const float* bv, float* out, int N) {
    __shared__ unsigned long long lp[CAP];    // 48KB sorted payload
    __shared__ unsigned wcnt[16][BINSZ];      // 8KB per-wave rank counts
    __shared__ float spill[BINSZ][8];         // 4KB overflow accumulator
    __shared__ float sag[BINSZ][8];           // 4KB per-node result vector
    __shared__ unsigned loc[BINSZ];
    __shared__ unsigned nxt[BINSZ];           // running per-lc base
    const float4* y4 = (const float4*)y;
    int b = blockIdx.x, t = threadIdx.x, lane = t & 63, wv = t >> 6;
    unsigned base = offs[b], len = offs[b + 1] - base;
    ((float*)spill)[t] = 0.f;                 // 1024 floats exactly
    if (t < BINSZ) {
        int node = b * BINSZ + t;
        unsigned l = (node < N) ? (noffs[node] - base) : len;
        loc[t] = l; nxt[t] = l;
    }
    __syncthreads();
    // stage rounds of <=6144 edges
    for (unsigned rbase = 0; rbase < len; rbase += (unsigned)CAP) {
        unsigned rend = rbase + (unsigned)CAP;
        if (rend > len) rend = len;
        for (int i = t; i < 16 * BINSZ; i += 1024) ((unsigned*)wcnt)[i] = 0u;
        __syncthreads();
        unsigned long long pr[EPT]; unsigned lcr[EPT], rkr[EPT];
        int kn = 0;
        for (unsigned j = rbase + t; j < rend; j += 1024) {
            unsigned long long p = pay[base + j];
            unsigned lc = (unsigned)p & 255u;
            pr[kn] = p; lcr[kn] = lc;
            rkr[kn] = atomicAdd(&wcnt[wv][lc], 1u);
            ++kn;
        }
        __syncthreads();
        // column scan: thread t<128 owns lc=t; per-(wave,lc) exclusive bases
        if (t < BINSZ) {
            unsigned run = nxt[t];
            #pragma unroll
            for (int w = 0; w < 16; ++w) {
                unsigned c = wcnt[w][t];
                wcnt[w][t] = run;
                run += c;
            }
            nxt[t] = run;
        }
        __syncthreads();
        for (int k = 0; k < kn; ++k) {
            unsigned pos = wcnt[wv][lcr[k]] + rkr[k];
            if (pos < CAP) lp[pos] = pr[k];
            else {                             // pathological overflow (corr.)
                unsigned r = ((unsigned)pr[k] >> 8) & 0xFFFFFFu;
                float ew = __uint_as_float((unsigned)(pr[k] >> 32));
                float4 u = y4[(size_t)r * 2], v = y4[(size_t)r * 2 + 1];
                unsigned lc = lcr[k];
                atomicAdd(&spill[lc][0], ew * u.x); atomicAdd(&spill[lc][1], ew * u.y);
                atomicAdd(&spill[lc][2], ew * u.z); atomicAdd(&spill[lc][3], ew * u.w);
                atomicAdd(&spill[lc][4], ew * v.x); atomicAdd(&spill[lc][5], ew * v.y);
                atomicAdd(&spill[lc][6], ew * v.z); atomicAdd(&spill[lc][7], ew * v.w);
            }
        }
        __syncthreads();
    }
    // accumulate: 4 nodes/wave, 8 slots x 2 f4-halves per node
    int quad = lane >> 4;                     // node sub-index 0..3
    int l4 = lane & 15;
    int slot = l4 >> 1, h = l4 & 1;
    for (int i = 0; i < 2; ++i) {
        int ln = wv + ((4 * i + quad) << 4);  // wv + 16k, k = 4i+quad
        int node = b * BINSZ + ln;
        float a0 = 0.f, a1 = 0.f, a2 = 0.f, a3 = 0.f;
        if (node < N) {
            unsigned s = loc[ln] + slot;
            unsigned e = (ln < BINSZ - 1) ? loc[ln + 1] : len;
            e = e < CAP ? e : CAP;
            for (unsigned j = s; j < e; j += 8) {
                unsigned long long p = lp[j];
                unsigned r = ((unsigned)p >> 8) & 0xFFFFFFu;
                float ew = __uint_as_float((unsigned)(p >> 32));
                float4 v = y4[(size_t)r * 2 + h];
                a0 += ew * v.x; a1 += ew * v.y; a2 += ew * v.z; a3 += ew * v.w;
            }
        }
        #pragma unroll
        for (int m = 2; m <= 8; m <<= 1) {    // within 16-lane groups
            a0 += __shfl_xor(a0, m); a1 += __shfl_xor(a1, m);
            a2 += __shfl_xor(a2, m); a3 += __shfl_xor(a3, m);
        }
        if (slot == 0 && node < N) {          // lanes l4 = 0 (h=0), 1 (h=1)
            float dc = dis[node];
            float4 vy = y4[(size_t)node * 2 + h];
            sag[ln][h * 4 + 0] = dc * (a0 + spill[ln][h * 4 + 0] + vy.x);
            sag[ln][h * 4 + 1] = dc * (a1 + spill[ln][h * 4 + 1] + vy.y);
            sag[ln][h * 4 + 2] = dc * (a2 + spill[ln][h * 4 + 2] + vy.z);
            sag[ln][h * 4 + 3] = dc * (a3 + spill[ln][h * 4 + 3] + vy.w);
        }
    }
    __syncthreads();
    float wr[8];
    #pragma unroll
    for (int k = 0; k < 8; ++k) wr[k] = Wm[k * 64 + lane];
    float bj = bv[lane];
    for (int i = 0; i < 8; ++i) {
        int ln = wv + (i << 4);
        int node = b * BINSZ + ln;
        if (node < N) {
            float o = bj;
            #pragma unroll
            for (int k = 0; k < 8; ++k) o += sag[ln][k] * wr[k];
            out[(size_t)node * 64 + lane] = o;
        }
    }
}

// ---------------- round-1 fallback (tiny ws / huge N) ----------------
__global__ void fb_init_k(const unsigned* w, unsigned* orw, float* deg,
                          float4* agg4, int N, int E) {
    int i = blockIdx.x * blockDim.x + threadIdx.x, st = gridDim.x * blockDim.x;
    for (; i < N; i += st) {
        deg[i] = 1.0f;
        agg4[2 * i] = make_float4(0.f, 0.f, 0.f, 0.f);
        agg4[2 * i + 1] = make_float4(0.f, 0.f, 0.f, 0.f);
    }
    if (blockIdx.x == 0) {
        __shared__ unsigned s;
        if (threadIdx.x == 0) s = 0u;
        __syncthreads();
        unsigned v = 0;
        int lim = (E < 2048) ? E : 2048;
        for (int k = threadIdx.x; k < lim; k += blockDim.x) v |= w[2 * k + 1];
        atomicOr(&s, v);
        __syncthreads();
        if (threadIdx.x == 0) *orw = s;
    }
}
__global__ void fb_deg_k(const void* ei, const float* ea, const unsigned* orw,
                         float* deg, int E) {
    const bool is64 = (*orw == 0u);
    const int* e32 = (const int*)ei;
    const long long* e64 = (const long long*)ei;
    int e = blockIdx.x * blockDim.x + threadIdx.x, st = gridDim.x * blockDim.x;
    for (; e < E; e += st) {
        int c = is64 ? (int)e64[E + e] : e32[E + e];
        atomicAdd(&deg[c], ea[e]);
    }
}
__global__ void fb_dis_k(float* deg, int N) {
    int i = blockIdx.x * blockDim.x + threadIdx.x, st = gridDim.x * blockDim.x;
    for (; i < N; i += st) {
        float d = deg[i];
        deg[i] = (d > 0.f) ? rsqrtf(d) : 0.f;
    }
}
__global__ void fb_edge_k(const void* ei, const float* ea, const unsigned* orw,
                          const float* dis, const float* x, float* agg, int E) {
    const bool is64 = (*orw == 0u);
    const int* e32 = (const int*)ei;
    const long long* e64 = (const long long*)ei;
    int e = blockIdx.x * blockDim.x + threadIdx.x, st = gridDim.x * blockDim.x;
    for (; e < E; e += st) {
        int r, c;
        if (is64) { r = (int)e64[e]; c = (int)e64[E + e]; }
        else      { r = e32[e];      c = e32[E + e]; }
        float nrm = dis[r] * ea[e] * dis[c];
        const float4* xr = (const float4*)(x + (size_t)r * 8);
        float4 a = xr[0], bb = xr[1];
        float* ag = agg + (size_t)c * 8;
        atomicAdd(ag + 0, nrm * a.x);  atomicAdd(ag + 1, nrm * a.y);
        atomicAdd(ag + 2, nrm * a.z);  atomicAdd(ag + 3, nrm * a.w);
        atomicAdd(ag + 4, nrm * bb.x); atomicAdd(ag + 5, nrm * bb.y);
        atomicAdd(ag + 6, nrm * bb.z); atomicAdd(ag + 7, nrm * bb.w);
    }
}
__global__ void fb_out_k(const float* x, const float* Wm, const float* bv,
                         const float* dis, const float* agg, float* out, int N) {
    int lane = threadIdx.x & 63;
    int wid = blockIdx.x * (blockDim.x >> 6) + (threadIdx.x >> 6);
    int nw = gridDim.x * (blockDim.x >> 6);
    float wr[8];
    #pragma unroll
    for (int k = 0; k < 8; ++k) wr[k] = Wm[k * 64 + lane];
    float bj = bv[lane];
    for (int i = wid; i < N; i += nw) {
        float d = dis[i];
        float ink = 0.f;
        if (lane < 8) ink = agg[(size_t)i * 8 + lane] + d * d * x[(size_t)i * 8 + lane];
        float acc = bj;
        #pragma unroll
        for (int k = 0; k < 8; ++k) acc += __shfl(ink, k) * wr[k];
        out[(size_t)i * 64 + lane] = acc;
    }
}

extern "C" void kernel_launch(void* const* d_in, const int* in_sizes, int n_in,
                              void* d_out, int out_size, void* d_ws, size_t ws_size,
                              hipStream_t stream) {
    const float* x  = (const float*)d_in[0];
    const void*  ei = d_in[1];
    const float* ea = (const float*)d_in[2];
    const float* Wm = (const float*)d_in[3];
    const float* bv = (const float*)d_in[4];
    float* out = (float*)d_out;

    const int N = in_sizes[0] / 8;
    const int E = in_sizes[2];
    const int NB = (N + BINSZ - 1) / BINSZ;
    const int ntiles = (E + TILE - 1) / TILE;
    const int cpx = (ntiles + 7) / 8;

    char* ws = (char*)d_ws;
    size_t o = 0;
    unsigned* orw   = (unsigned*)(ws + o); o += 256;   // fallback only
    unsigned* cnt   = (unsigned*)(ws + o); o += ws_align(NBMAX * 4);
    unsigned* offs  = (unsigned*)(ws + o); o += ws_align((NBMAX + 1) * 4);
    float* dis      = (float*)(ws + o);    o += ws_align((size_t)N * 4);
    unsigned* noffs = (unsigned*)(ws + o); o += ws_align((size_t)(N + 1) * 4);
    float* y        = (float*)(ws + o);    o += ws_align((size_t)N * 8 * 4);
    unsigned* tcnt  = (unsigned*)(ws + o); o += ws_align((size_t)ntiles * NB * 4);
    unsigned long long* pay = (unsigned long long*)(ws + o);
    o += ws_align((size_t)E * 8);

    if (NB <= NBMAX && E >= 2048 && o <= ws_size) {
        int hgrid = ntiles < 2048 ? ntiles : 2048;
        int sgrid = cpx * 8 < 2048 ? cpx * 8 : 2048;
        hist_k<<<hgrid, 1024, 0, stream>>>(ei, tcnt, E, NB, ntiles);
        scan2_k<<<NB, 64, 0, stream>>>(tcnt, cnt, NB, ntiles);
        scan_k<<<1, 1024, 0, stream>>>(cnt, offs, NB);
        scat_k<<<sgrid, 1024, 0, stream>>>(ei, ea, offs, tcnt, pay, E, NB,
                                           ntiles, cpx);
        nodestat_k<<<NB, 1024, 0, stream>>>(pay, offs, noffs, dis, x, y, N, E);
        aggfuse_k<<<NB, 1024, 0, stream>>>(pay, offs, noffs, dis, y, Wm, bv, out, N);
    } else {
        float* agg = (float*)(ws + 256 + ws_align((size_t)N * 4));
        fb_init_k<<<(N + 255) / 256, 256, 0, stream>>>((const unsigned*)ei, orw,
                                                       dis, (float4*)agg, N, E);
        fb_deg_k<<<2048, 256, 0, stream>>>(ei, ea, orw, dis, E);
        fb_dis_k<<<(N + 255) / 256, 256, 0, stream>>>(dis, N);
        fb_edge_k<<<2048, 256, 0, stream>>>(ei, ea, orw, dis, x, agg, E);
        fb_out_k<<<2048, 256, 0, stream>>>(x, Wm, bv, dis, agg, out, N);
    }
}

// Round 18
// 104.742 us; speedup vs baseline: 1.0290x; 1.0290x over previous
//
#include <hip/hip_runtime.h>

// GCNConv(8->64), self-loops, symmetric norm.
// out[c] = ( dis[c] * sum_e dis[r]*ew*x[r]  +  dis[c]^2 * x[c] ) @ W + b
//
// v18 = v16 (measured best: 105.8us). r17's per-wave atomic split reverted
// (regressed: independent contended LDS atomics were not the cost; r15's
// pathology was dependent same-row atomic chains).
// Pipeline: per-tile hist -> 2D scans (zero global atomics) -> staged-LDS
// scatter (coalesced runs, XCD-swizzled tile order) -> nodestat (dis, y,
// noffs) -> fused node-sort + register reduce (3 shfl/node) + 8->64
// transform + bias.
//
// Payload pack (u64): ew_bits(32) | row(24) | lcol(8). Valid for N <= 2^24.

#define NBMAX 1024          // max bins => N <= 131072 (fallback beyond)
#define PSH   7
#define BINSZ 128
#define TILE  6144          // edges per tile
#define EPT   6             // TILE / 1024 threads
#define CAP   6144          // max edges per bin staged in LDS by aggfuse

static inline size_t ws_align(size_t x) { return (x + 255) & ~(size_t)255; }

// per-block int64-layout detect: odd 32-bit words of int64 indices (<2^31)
// are all zero; random int32 col values make the OR nonzero essentially surely.
__device__ __forceinline__ bool detect64(const unsigned* w, int E) {
    __shared__ unsigned det;
    if (threadIdx.x == 0) det = 0u;
    __syncthreads();
    int lim = E < 1024 ? E : 1024;
    unsigned v = 0;
    for (int i = threadIdx.x; i < lim; i += blockDim.x) v |= w[2 * i + 1];
    if (v) atomicOr(&det, 1u);
    __syncthreads();
    return det == 0u;
}

// ---- per-tile histogram over destination bins -> tcnt[tile][bin] ----
__global__ __launch_bounds__(1024)
void hist_k(const void* ei, unsigned* tcnt, int E, int NB, int ntiles) {
    __shared__ unsigned lh[NBMAX];
    const bool is64 = detect64((const unsigned*)ei, E);
    const int* e32 = (const int*)ei;
    const long long* e64 = (const long long*)ei;
    const int t = threadIdx.x;
    for (int tile = blockIdx.x; tile < ntiles; tile += gridDim.x) {
        int base = tile * TILE;
        int tc = E - base; if (tc > TILE) tc = TILE;
        for (int i = t; i < NB; i += 1024) lh[i] = 0u;
        __syncthreads();
        for (int e = base + t; e < base + tc; e += 1024) {
            int c = is64 ? (int)e64[E + e] : e32[E + e];
            atomicAdd(&lh[c >> PSH], 1u);
        }
        __syncthreads();
        for (int i = t; i < NB; i += 1024)
            tcnt[(size_t)tile * NB + i] = lh[i];
        __syncthreads();
    }
}

// ---- column scan: tcnt[:, b] -> exclusive prefix (in place) + cnt[b] ----
__global__ void scan2_k(unsigned* tcnt, unsigned* cnt, int NB, int ntiles) {
    int b = blockIdx.x, lane = threadIdx.x;   // 64 threads
    unsigned run = 0;
    for (int base = 0; base < ntiles; base += 64) {
        int i = base + lane;
        unsigned v = (i < ntiles) ? tcnt[(size_t)i * NB + b] : 0u;
        unsigned s = v;
        #pragma unroll
        for (int d = 1; d < 64; d <<= 1) {
            unsigned u = __shfl_up(s, d);
            if (lane >= d) s += u;
        }
        if (i < ntiles) tcnt[(size_t)i * NB + b] = run + s - v;
        run += __shfl(s, 63);
    }
    if (lane == 0) cnt[b] = run;
}

// ---- exclusive scan of cnt[NB] -> offs[NB+1] (shfl) ----
__global__ void scan_k(const unsigned* cnt, unsigned* offs, int NB) {
    __shared__ unsigned wsum[16];
    int t = threadIdx.x, lane = t & 63, wv = t >> 6;   // 1024 threads
    unsigned v0 = (t < NB) ? cnt[t] : 0u;
    unsigned s = v0;
    #pragma unroll
    for (int d = 1; d < 64; d <<= 1) {
        unsigned u = __shfl_up(s, d);
        if (lane >= d) s += u;
    }
    if (lane == 63) wsum[wv] = s;
    __syncthreads();
    if (t < 16) {
        unsigned w = wsum[t];
        #pragma unroll
        for (int d = 1; d < 16; d <<= 1) {
            unsigned u = __shfl_up(w, d, 16);
            if (t >= d) w += u;
        }
        wsum[t] = w;
    }
    __syncthreads();
    unsigned excl = s - v0 + (wv ? wsum[wv - 1] : 0u);
    if (t < NB) offs[t] = excl;
    if (t == NB - 1) offs[NB] = excl + v0;
}

// ---- scatter: staged LDS bin-sort, deterministic run bases, coalesced
// flush; XCD-swizzled tile order (adjacent tiles -> same XCD) ----
__global__ __launch_bounds__(1024)
void scat_k(const void* ei, const float* ea, const unsigned* offs,
            const unsigned* tcnt, unsigned long long* pay,
            int E, int NB, int ntiles, int cpx) {
    __shared__ unsigned long long lp[TILE];   // 48KB
    __shared__ unsigned short lbin[TILE];     // 12KB
    __shared__ unsigned lh[NBMAX];
    __shared__ unsigned lo[NBMAX];
    __shared__ unsigned tb[NBMAX];
    __shared__ unsigned wsum[16];
    const bool is64 = detect64((const unsigned*)ei, E);
    const int* e32 = (const int*)ei;
    const long long* e64 = (const long long*)ei;
    const int t = threadIdx.x, lane = t & 63, wv = t >> 6;
    const int sgrid = cpx * 8;

    for (int ii = blockIdx.x; ii < sgrid; ii += gridDim.x) {
        int tile = (ii & 7) * cpx + (ii >> 3);   // XCD-contiguous chunks
        if (tile >= ntiles) continue;
        int base = tile * TILE;
        int tc = E - base; if (tc > TILE) tc = TILE;

        for (int i = t; i < NB; i += 1024) lh[i] = 0u;
        __syncthreads();

        int bn[EPT]; unsigned rk[EPT]; unsigned long long pv[EPT];
        #pragma unroll
        for (int i = 0; i < EPT; ++i) {
            int e = base + i * 1024 + t;
            bn[i] = -1;
            if (e < base + tc) {
                int c, r;
                if (is64) { c = (int)e64[E + e]; r = (int)e64[e]; }
                else      { c = e32[E + e];      r = e32[e]; }
                float w = ea[e];
                bn[i] = c >> PSH;
                pv[i] = ((unsigned long long)__float_as_uint(w) << 32)
                        | ((unsigned)r << 8) | (unsigned)(c & (BINSZ - 1));
                rk[i] = atomicAdd(&lh[bn[i]], 1u);
            }
        }
        __syncthreads();

        unsigned v0 = (t < NB) ? lh[t] : 0u;
        unsigned s = v0;
        #pragma unroll
        for (int d = 1; d < 64; d <<= 1) {
            unsigned u = __shfl_up(s, d);
            if (lane >= d) s += u;
        }
        if (lane == 63) wsum[wv] = s;
        __syncthreads();
        if (t < 16) {
            unsigned w = wsum[t];
            #pragma unroll
            for (int d = 1; d < 16; d <<= 1) {
                unsigned u = __shfl_up(w, d, 16);
                if (t >= d) w += u;
            }
            wsum[t] = w;
        }
        __syncthreads();
        unsigned excl = s - v0 + (wv ? wsum[wv - 1] : 0u);
        if (t < NB) {
            lo[t] = excl;
            tb[t] = offs[t] + tcnt[(size_t)tile * NB + t];
        }
        __syncthreads();

        #pragma unroll
        for (int i = 0; i < EPT; ++i)
            if (bn[i] >= 0) {
                unsigned pos = lo[bn[i]] + rk[i];
                lp[pos] = pv[i];
                lbin[pos] = (unsigned short)bn[i];
            }
        __syncthreads();

        // flush: coalesced per-run segments
        for (int q = t; q < tc; q += 1024) {
            int a = lbin[q];
            pay[(size_t)tb[a] + (unsigned)q - lo[a]] = lp[q];
        }
        __syncthreads();
    }
}

// ---- A: per-bin node stats -> noffs, dis, y = dis*x ----
__global__ __launch_bounds__(1024)
void nodestat_k(const unsigned long long* pay, const unsigned* offs,
                unsigned* noffs, float* dis, const float* x, float* y,
                int N, int E) {
    __shared__ unsigned cnt[BINSZ];
    __shared__ float dw[BINSZ];
    __shared__ float sdis[BINSZ];
    __shared__ unsigned wpart[2];
    int b = blockIdx.x, t = threadIdx.x, lane = t & 63, wv = t >> 6;
    if (t < BINSZ) { cnt[t] = 0u; dw[t] = 0.f; }
    if (b == 0 && t == 0) noffs[N] = (unsigned)E;
    __syncthreads();
    unsigned base = offs[b], len = offs[b + 1] - base;
    for (unsigned j = t; j < len; j += 1024) {
        unsigned long long p = pay[base + j];
        unsigned lc = (unsigned)p & 255u;
        atomicAdd(&cnt[lc], 1u);
        atomicAdd(&dw[lc], __uint_as_float((unsigned)(p >> 32)));
    }
    __syncthreads();
    unsigned v0 = (t < BINSZ) ? cnt[t] : 0u;
    unsigned s = v0;
    #pragma unroll
    for (int d = 1; d < 64; d <<= 1) {
        unsigned u = __shfl_up(s, d);
        if (lane >= d) s += u;
    }
    if (t < BINSZ && lane == 63) wpart[wv] = s;
    __syncthreads();
    if (t < BINSZ) {
        unsigned excl = s - v0 + (wv == 1 ? wpart[0] : 0u);
        int node = b * BINSZ + t;
        float dval = 0.f;
        if (node < N) {
            noffs[node] = base + excl;
            float d = 1.0f + dw[t];
            dval = (d > 0.f) ? rsqrtf(d) : 0.f;
            dis[node] = dval;
        }
        sdis[t] = dval;
    }
    __syncthreads();
    int gi = b * (BINSZ * 8) + t;             // 1024 == BINSZ*8
    if (gi < N * 8) y[gi] = sdis[t >> 3] * x[gi];
}

// ---- B: fused per-bin node-sort (LDS) + aggregate + transform + out ----
// accumulate: 4 nodes per wave (16-lane groups), 8 slots x 2 f4-halves;
// shfl tree masks {2,4,8} shared by 4 nodes -> 3 shfls/node.
__global__ __launch_bounds__(1024)
void aggfuse_k(const unsigned long long* pay, const unsigned* offs,
               const unsigned* noffs, const float* dis, const float* y,
               const float* Wm, const float* bv, float* out, int N) {
    __shared__ unsigned long long lp[CAP];    // 48KB sorted payload
    __shared__ float spill[BINSZ][8];         // 4KB overflow accumulator
    __shared__ float sag[BINSZ][8];           // 4KB per-node result vector
    __shared__ unsigned loc[BINSZ];
    __shared__ unsigned cur[BINSZ];
    const float4* y4 = (const float4*)y;
    int b = blockIdx.x, t = threadIdx.x, lane = t & 63, wv = t >> 6;
    unsigned base = offs[b], len = offs[b + 1] - base;
    ((float*)spill)[t] = 0.f;                 // 1024 floats exactly
    if (t < BINSZ) {
        int node = b * BINSZ + t;
        unsigned l = (node < N) ? (noffs[node] - base) : len;
        loc[t] = l; cur[t] = l;
    }
    __syncthreads();
    for (unsigned j = t; j < len; j += 1024) {
        unsigned long long p = pay[base + j];
        unsigned lc = (unsigned)p & 255u;
        unsigned pos = atomicAdd(&cur[lc], 1u);
        if (pos < CAP) lp[pos] = p;
        else {                                 // pathological overflow (corr.)
            unsigned r = ((unsigned)p >> 8) & 0xFFFFFFu;
            float ew = __uint_as_float((unsigned)(p >> 32));
            float4 u = y4[(size_t)r * 2], v = y4[(size_t)r * 2 + 1];
            atomicAdd(&spill[lc][0], ew * u.x); atomicAdd(&spill[lc][1], ew * u.y);
            atomicAdd(&spill[lc][2], ew * u.z); atomicAdd(&spill[lc][3], ew * u.w);
            atomicAdd(&spill[lc][4], ew * v.x); atomicAdd(&spill[lc][5], ew * v.y);
            atomicAdd(&spill[lc][6], ew * v.z); atomicAdd(&spill[lc][7], ew * v.w);
        }
    }
    __syncthreads();
    // accumulate: 4 nodes/wave, 8 slots x 2 halves per node
    int quad = lane >> 4;                     // node sub-index 0..3
    int l4 = lane & 15;
    int slot = l4 >> 1, h = l4 & 1;
    for (int i = 0; i < 2; ++i) {
        int ln = wv + ((4 * i + quad) << 4);  // wv + 16k, k = 4i+quad
        int node = b * BINSZ + ln;
        float a0 = 0.f, a1 = 0.f, a2 = 0.f, a3 = 0.f;
        if (node < N) {
            unsigned s = loc[ln] + slot;
            unsigned e = (ln < BINSZ - 1) ? loc[ln + 1] : len;
            e = e < CAP ? e : CAP;
            for (unsigned j = s; j < e; j += 8) {
                unsigned long long p = lp[j];
                unsigned r = ((unsigned)p >> 8) & 0xFFFFFFu;
                float ew = __uint_as_float((unsigned)(p >> 32));
                float4 v = y4[(size_t)r * 2 + h];
                a0 += ew * v.x; a1 += ew * v.y; a2 += ew * v.z; a3 += ew * v.w;
            }
        }
        #pragma unroll
        for (int m = 2; m <= 8; m <<= 1) {    // within 16-lane groups
            a0 += __shfl_xor(a0, m); a1 += __shfl_xor(a1, m);
            a2 += __shfl_xor(a2, m); a3 += __shfl_xor(a3, m);
        }
        if (slot == 0 && node < N) {          // lanes l4 = 0 (h=0), 1 (h=1)
            float dc = dis[node];
            float4 vy = y4[(size_t)node * 2 + h];
            sag[ln][h * 4 + 0] = dc * (a0 + spill[ln][h * 4 + 0] + vy.x);
            sag[ln][h * 4 + 1] = dc * (a1 + spill[ln][h * 4 + 1] + vy.y);
            sag[ln][h * 4 + 2] = dc * (a2 + spill[ln][h * 4 + 2] + vy.z);
            sag[ln][h * 4 + 3] = dc * (a3 + spill[ln][h * 4 + 3] + vy.w);
        }
    }
    __syncthreads();
    float wr[8];
    #pragma unroll
    for (int k = 0; k < 8; ++k) wr[k] = Wm[k * 64 + lane];
    float bj = bv[lane];
    for (int i = 0; i < 8; ++i) {
        int ln = wv + (i << 4);
        int node = b * BINSZ + ln;
        if (node < N) {
            float o = bj;
            #pragma unroll
            for (int k = 0; k < 8; ++k) o += sag[ln][k] * wr[k];
            out[(size_t)node * 64 + lane] = o;
        }
    }
}

// ---------------- round-1 fallback (tiny ws / huge N) ----------------
__global__ void fb_init_k(const unsigned* w, unsigned* orw, float* deg,
                          float4* agg4, int N, int E) {
    int i = blockIdx.x * blockDim.x + threadIdx.x, st = gridDim.x * blockDim.x;
    for (; i < N; i += st) {
        deg[i] = 1.0f;
        agg4[2 * i] = make_float4(0.f, 0.f, 0.f, 0.f);
        agg4[2 * i + 1] = make_float4(0.f, 0.f, 0.f, 0.f);
    }
    if (blockIdx.x == 0) {
        __shared__ unsigned s;
        if (threadIdx.x == 0) s = 0u;
        __syncthreads();
        unsigned v = 0;
        int lim = (E < 2048) ? E : 2048;
        for (int k = threadIdx.x; k < lim; k += blockDim.x) v |= w[2 * k + 1];
        atomicOr(&s, v);
        __syncthreads();
        if (threadIdx.x == 0) *orw = s;
    }
}
__global__ void fb_deg_k(const void* ei, const float* ea, const unsigned* orw,
                         float* deg, int E) {
    const bool is64 = (*orw == 0u);
    const int* e32 = (const int*)ei;
    const long long* e64 = (const long long*)ei;
    int e = blockIdx.x * blockDim.x + threadIdx.x, st = gridDim.x * blockDim.x;
    for (; e < E; e += st) {
        int c = is64 ? (int)e64[E + e] : e32[E + e];
        atomicAdd(&deg[c], ea[e]);
    }
}
__global__ void fb_dis_k(float* deg, int N) {
    int i = blockIdx.x * blockDim.x + threadIdx.x, st = gridDim.x * blockDim.x;
    for (; i < N; i += st) {
        float d = deg[i];
        deg[i] = (d > 0.f) ? rsqrtf(d) : 0.f;
    }
}
__global__ void fb_edge_k(const void* ei, const float* ea, const unsigned* orw,
                          const float* dis, const float* x, float* agg, int E) {
    const bool is64 = (*orw == 0u);
    const int* e32 = (const int*)ei;
    const long long* e64 = (const long long*)ei;
    int e = blockIdx.x * blockDim.x + threadIdx.x, st = gridDim.x * blockDim.x;
    for (; e < E; e += st) {
        int r, c;
        if (is64) { r = (int)e64[e]; c = (int)e64[E + e]; }
        else      { r = e32[e];      c = e32[E + e]; }
        float nrm = dis[r] * ea[e] * dis[c];
        const float4* xr = (const float4*)(x + (size_t)r * 8);
        float4 a = xr[0], bb = xr[1];
        float* ag = agg + (size_t)c * 8;
        atomicAdd(ag + 0, nrm * a.x);  atomicAdd(ag + 1, nrm * a.y);
        atomicAdd(ag + 2, nrm * a.z);  atomicAdd(ag + 3, nrm * a.w);
        atomicAdd(ag + 4, nrm * bb.x); atomicAdd(ag + 5, nrm * bb.y);
        atomicAdd(ag + 6, nrm * bb.z); atomicAdd(ag + 7, nrm * bb.w);
    }
}
__global__ void fb_out_k(const float* x, const float* Wm, const float* bv,
                         const float* dis, const float* agg, float* out, int N) {
    int lane = threadIdx.x & 63;
    int wid = blockIdx.x * (blockDim.x >> 6) + (threadIdx.x >> 6);
    int nw = gridDim.x * (blockDim.x >> 6);
    float wr[8];
    #pragma unroll
    for (int k = 0; k < 8; ++k) wr[k] = Wm[k * 64 + lane];
    float bj = bv[lane];
    for (int i = wid; i < N; i += nw) {
        float d = dis[i];
        float ink = 0.f;
        if (lane < 8) ink = agg[(size_t)i * 8 + lane] + d * d * x[(size_t)i * 8 + lane];
        float acc = bj;
        #pragma unroll
        for (int k = 0; k < 8; ++k) acc += __shfl(ink, k) * wr[k];
        out[(size_t)i * 64 + lane] = acc;
    }
}

extern "C" void kernel_launch(void* const* d_in, const int* in_sizes, int n_in,
                              void* d_out, int out_size, void* d_ws, size_t ws_size,
                              hipStream_t stream) {
    const float* x  = (const float*)d_in[0];
    const void*  ei = d_in[1];
    const float* ea = (const float*)d_in[2];
    const float* Wm = (const float*)d_in[3];
    const float* bv = (const float*)d_in[4];
    float* out = (float*)d_out;

    const int N = in_sizes[0] / 8;
    const int E = in_sizes[2];
    const int NB = (N + BINSZ - 1) / BINSZ;
    const int ntiles = (E + TILE - 1) / TILE;
    const int cpx = (ntiles + 7) / 8;

    char* ws = (char*)d_ws;
    size_t o = 0;
    unsigned* orw   = (unsigned*)(ws + o); o += 256;   // fallback only
    unsigned* cnt   = (unsigned*)(ws + o); o += ws_align(NBMAX * 4);
    unsigned* offs  = (unsigned*)(ws + o); o += ws_align((NBMAX + 1) * 4);
    float* dis      = (float*)(ws + o);    o += ws_align((size_t)N * 4);
    unsigned* noffs = (unsigned*)(ws + o); o += ws_align((size_t)(N + 1) * 4);
    float* y        = (float*)(ws + o);    o += ws_align((size_t)N * 8 * 4);
    unsigned* tcnt  = (unsigned*)(ws + o); o += ws_align((size_t)ntiles * NB * 4);
    unsigned long long* pay = (unsigned long long*)(ws + o);
    o += ws_align((size_t)E * 8);

    if (NB <= NBMAX && E >= 2048 && o <= ws_size) {
        int hgrid = ntiles < 2048 ? ntiles : 2048;
        int sgrid = cpx * 8 < 2048 ? cpx * 8 : 2048;
        hist_k<<<hgrid, 1024, 0, stream>>>(ei, tcnt, E, NB, ntiles);
        scan2_k<<<NB, 64, 0, stream>>>(tcnt, cnt, NB, ntiles);
        scan_k<<<1, 1024, 0, stream>>>(cnt, offs, NB);
        scat_k<<<sgrid, 1024, 0, stream>>>(ei, ea, offs, tcnt, pay, E, NB,
                                           ntiles, cpx);
        nodestat_k<<<NB, 1024, 0, stream>>>(pay, offs, noffs, dis, x, y, N, E);
        aggfuse_k<<<NB, 1024, 0, stream>>>(pay, offs, noffs, dis, y, Wm, bv, out, N);
    } else {
        float* agg = (float*)(ws + 256 + ws_align((size_t)N * 4));
        fb_init_k<<<(N + 255) / 256, 256, 0, stream>>>((const unsigned*)ei, orw,
                                                       dis, (float4*)agg, N, E);
        fb_deg_k<<<2048, 256, 0, stream>>>(ei, ea, orw, dis, E);
        fb_dis_k<<<(N + 255) / 256, 256, 0, stream>>>(dis, N);
        fb_edge_k<<<2048, 256, 0, stream>>>(ei, ea, orw, dis, x, agg, E);
        fb_out_k<<<2048, 256, 0, stream>>>(x, Wm, bv, dis, agg, out, N);
    }
}